// Round 3
// baseline (275.543 us; speedup 1.0000x reference)
//
#include <hip/hip_runtime.h>
#include <math.h>

#define B_   8
#define C_   128
#define H_   128
#define W_   128
#define TX   32
#define TY   32
#define VPX  4                    // vertical pixels per thread
#define PAD  3
#define HX   (TX + 2*PAD)         // 38
#define HY   (TY + 2*PAD)         // 38
#define NPOS (HX*HY)              // 1444
#define NC   4                    // channels per LDS float4
#define CPB  32                   // channels per block
#define NGRP (CPB/NC)             // 8
#define NCHUNK (C_/CPB)           // 4
#define NSLOT 6                   // ceil(1444/256)
#define REM  (NPOS - 5*256)       // 164

typedef float v2f __attribute__((ext_vector_type(2)));

struct KTab { float sk[4][7][8]; };   // 4 dirs x 7 rows x 8 taps (tap 7 = 0 pad)

__device__ __forceinline__ int refl(int i, int n) {
    if (i < 0) i = -i;
    if (i >= n) i = 2*n - 2 - i;
    return i;
}

__global__ __launch_bounds__(256, 2) void ddconv_kernel(
    const float* __restrict__ x,      // [B,C,H,W]
    const float* __restrict__ angle,  // [B,H,W]
    const float* __restrict__ w1,     // [8,2]
    const float* __restrict__ b1,     // [8]
    const float* __restrict__ w2,     // [4,8]
    const float* __restrict__ b2,     // [4]
    float* __restrict__ out,          // [B,C,H,W]
    KTab kt)
{
    __shared__ float4 buf[2][NPOS];   // 2 * 1444 * 16 B = 46208 B

    const int tid = threadIdx.x;
    const int tx  = tid & 31;          // 0..31
    const int tr  = tid >> 5;          // 0..7 -> output rows VPX*tr .. VPX*tr+3
    const int bx  = blockIdx.x;        // 16 tiles (4x4)
    const int TX0 = (bx & 3) * TX;
    const int TY0 = (bx >> 2) * TY;
    const int b   = blockIdx.y;
    const int c0  = blockIdx.z * CPB;
    const int y0  = TY0 + VPX*tr;
    const int wv  = TX0 + tx;
    const size_t HW = (size_t)H_ * W_;

    // ---- staging geometry ----
    int off[NSLOT];
#pragma unroll
    for (int s = 0; s < NSLOT; ++s) {
        int p = tid + s*256;
        if (p >= NPOS) p = NPOS - 1;
        int gy = refl(TY0 + p/HX - PAD, H_);
        int gx = refl(TX0 + p%HX - PAD, W_);
        off[s] = gy*W_ + gx;
    }
    const bool hasR = (tid < REM);

    // ---- prologue: issue group-0 stage loads ----
    float4 pv[NSLOT];
    {
        const float* xb = x + ((size_t)(b*C_ + c0))*HW;
#pragma unroll
        for (int s = 0; s < NSLOT; ++s) {
            if (s == NSLOT-1 && !hasR) break;
            pv[s].x = xb[0*HW + off[s]]; pv[s].y = xb[1*HW + off[s]];
            pv[s].z = xb[2*HW + off[s]]; pv[s].w = xb[3*HW + off[s]];
        }
    }

    // ---- per-pixel gating weights (overlaps with loads in flight) ----
    v2f wt2[VPX][4];
#pragma unroll
    for (int p = 0; p < VPX; ++p) {
        float a = angle[((size_t)b*H_ + (y0+p))*W_ + wv];
        float s = __sinf(2.f*a), c = __cosf(2.f*a);
        float hv[8];
#pragma unroll
        for (int j = 0; j < 8; ++j) {
            float v = fmaf(s, w1[2*j], fmaf(c, w1[2*j+1], b1[j]));
            hv[j] = v > 0.f ? v : 0.f;
        }
        float lg[4];
#pragma unroll
        for (int d = 0; d < 4; ++d) {
            float v = b2[d];
#pragma unroll
            for (int j = 0; j < 8; ++j) v = fmaf(hv[j], w2[d*8+j], v);
            lg[d] = v;
        }
        float m  = fmaxf(fmaxf(lg[0], lg[1]), fmaxf(lg[2], lg[3]));
        float e0 = __expf(lg[0]-m), e1 = __expf(lg[1]-m);
        float e2 = __expf(lg[2]-m), e3 = __expf(lg[3]-m);
        float inv = 1.f / (e0+e1+e2+e3);
        wt2[p][0] = (v2f){e0*inv, e0*inv};
        wt2[p][1] = (v2f){e1*inv, e1*inv};
        wt2[p][2] = (v2f){e2*inv, e2*inv};
        wt2[p][3] = (v2f){e3*inv, e3*inv};
    }

    // write group-0 tile
    {
#pragma unroll
        for (int s = 0; s < NSLOT; ++s) {
            if (s == NSLOT-1 && !hasR) break;
            buf[0][tid + s*256] = pv[s];
        }
    }

    for (int g = 0; g < NGRP; ++g) {
        __syncthreads();   // buf[g&1] ready; readers of buf[(g+1)&1] (iter g-1) done

        // issue next group's stage loads EARLY
        const bool doStage = (g + 1 < NGRP);
        if (doStage) {
            const float* xb = x + ((size_t)(b*C_ + c0 + (g+1)*NC))*HW;
#pragma unroll
            for (int s = 0; s < NSLOT; ++s) {
                if (s == NSLOT-1 && !hasR) break;
                pv[s].x = xb[0*HW + off[s]]; pv[s].y = xb[1*HW + off[s]];
                pv[s].z = xb[2*HW + off[s]]; pv[s].w = xb[3*HW + off[s]];
            }
        }

        // ---- conv: 4 vertical px x 4 channels, blend-on-the-fly ----
        const float4* tb = buf[g & 1];
        v2f aL[VPX], aH[VPX];
#pragma unroll
        for (int p = 0; p < VPX; ++p) { aL[p] = (v2f){0.f,0.f}; aH[p] = (v2f){0.f,0.f}; }

#pragma unroll
        for (int r = 0; r < VPX + 6; ++r) {
            float4 win[7];
            const int base = (VPX*tr + r)*HX + tx;
#pragma unroll
            for (int j = 0; j < 7; ++j) win[j] = tb[base + j];
#pragma unroll
            for (int p = 0; p < VPX; ++p) {
                const int i = r - p;
                if (i < 0 || i > 6) continue;
                // blend this kernel row from kernarg constants (scalar pipe)
                v2f kb2[4];
#pragma unroll
                for (int t = 0; t < 4; ++t) {
                    v2f s0 = {kt.sk[0][i][2*t], kt.sk[0][i][2*t+1]};
                    v2f s1 = {kt.sk[1][i][2*t], kt.sk[1][i][2*t+1]};
                    v2f s2 = {kt.sk[2][i][2*t], kt.sk[2][i][2*t+1]};
                    v2f s3 = {kt.sk[3][i][2*t], kt.sk[3][i][2*t+1]};
                    kb2[t] = wt2[p][0]*s0 + wt2[p][1]*s1 + wt2[p][2]*s2 + wt2[p][3]*s3;
                }
                const float* kb = (const float*)kb2;
#pragma unroll
                for (int j = 0; j < 7; ++j) {
                    v2f kk = {kb[j], kb[j]};
                    v2f lo = {win[j].x, win[j].y};
                    v2f hi = {win[j].z, win[j].w};
                    aL[p] += lo * kk;
                    aH[p] += hi * kk;
                }
            }
        }

        // ---- store 4 px x 4 ch ----
        float* ob = out + ((size_t)(b*C_ + c0 + g*NC))*HW + (size_t)y0*W_ + wv;
#pragma unroll
        for (int p = 0; p < VPX; ++p) {
            ob[p*W_ + 0*HW] = aL[p].x;
            ob[p*W_ + 1*HW] = aL[p].y;
            ob[p*W_ + 2*HW] = aH[p].x;
            ob[p*W_ + 3*HW] = aH[p].y;
        }

        // write-late: next group's tile into the other buffer
        if (doStage) {
            float4* nb = buf[(g+1) & 1];
#pragma unroll
            for (int s = 0; s < NSLOT; ++s) {
                if (s == NSLOT-1 && !hasR) break;
                nb[tid + s*256] = pv[s];
            }
        }
    }
}

static KTab make_ktab() {
    KTab t;
    const double sig1 = 2.5, sig2 = 1.0;
    const double angles[4] = {0.0, M_PI/4.0, M_PI/2.0, 3.0*M_PI/4.0};
    for (int d = 0; d < 4; ++d) {
        double th = angles[d], cs = cos(th), sn = sin(th);
        double sum = 0.0, k[7][7];
        for (int i = 0; i < 7; ++i) for (int j = 0; j < 7; ++j) {
            double xx = i - 3, yy = j - 3;
            double xr = xx*cs + yy*sn, yr = -xx*sn + yy*cs;
            k[i][j] = exp(-(xr*xr/(2.0*sig1*sig1) + yr*yr/(2.0*sig2*sig2)));
            sum += k[i][j];
        }
        for (int i = 0; i < 7; ++i) {
            for (int j = 0; j < 7; ++j) t.sk[d][i][j] = (float)(k[i][j]/sum);
            t.sk[d][i][7] = 0.f;
        }
    }
    return t;
}

extern "C" void kernel_launch(void* const* d_in, const int* in_sizes, int n_in,
                              void* d_out, int out_size, void* d_ws, size_t ws_size,
                              hipStream_t stream) {
    const float* x     = (const float*)d_in[0];
    const float* angle = (const float*)d_in[1];
    const float* w1    = (const float*)d_in[2];
    const float* b1    = (const float*)d_in[3];
    const float* w2    = (const float*)d_in[4];
    const float* b2    = (const float*)d_in[5];
    float* out = (float*)d_out;

    static const KTab kt = make_ktab();   // deterministic; host-side, no HIP calls

    dim3 grid((W_/TX)*(H_/TY), B_, NCHUNK);   // 16 x 8 x 4 = 512 blocks
    dim3 block(256);
    ddconv_kernel<<<grid, block, 0, stream>>>(x, angle, w1, b1, w2, b2, out, kt);
}

// Round 4
// 50.196 us; speedup vs baseline: 5.4894x; 5.4894x over previous
//
#include <hip/hip_runtime.h>
#include <math.h>

#define B_   8
#define C_   128
#define H_   128
#define W_   128
#define TX   32
#define TY   32
#define VPX  4                    // vertical pixels per thread
#define PAD  3
#define HX   (TX + 2*PAD)         // 38
#define HY   (TY + 2*PAD)         // 38
#define NPOS (HX*HY)              // 1444
#define NC   4                    // channels per LDS float4
#define CPB  32                   // channels per block
#define NGRP (CPB/NC)             // 8
#define NCHUNK (C_/CPB)           // 4
#define NSLOT 6                   // ceil(1444/256)
#define REM  (NPOS - 5*256)       // 164

// 25 symmetry-unique taps per direction: t = i*7+j for t<=24; K[t] == K[48-t]
struct KTab { float sk[4][25]; };

__device__ __forceinline__ int refl(int i, int n) {
    if (i < 0) i = -i;
    if (i >= n) i = 2*n - 2 - i;
    return i;
}

__global__ __launch_bounds__(256, 2) void ddconv_kernel(
    const float* __restrict__ x,      // [B,C,H,W]
    const float* __restrict__ angle,  // [B,H,W]
    const float* __restrict__ w1,     // [8,2]
    const float* __restrict__ b1,     // [8]
    const float* __restrict__ w2,     // [4,8]
    const float* __restrict__ b2,     // [4]
    float* __restrict__ out,          // [B,C,H,W]
    KTab kt)
{
    __shared__ float4 buf[2][NPOS];   // 46208 B

    const int tid = threadIdx.x;
    const int tx  = tid & 31;          // 0..31
    const int tr  = tid >> 5;          // 0..7 -> rows 4*tr .. 4*tr+3
    const int bx  = blockIdx.x;        // 16 tiles (4x4)
    const int TX0 = (bx & 3) * TX;
    const int TY0 = (bx >> 2) * TY;
    const int b   = blockIdx.y;
    const int c0  = blockIdx.z * CPB;
    const int y0  = TY0 + VPX*tr;
    const int wv  = TX0 + tx;
    const size_t HW = (size_t)H_ * W_;

    // ---- staging geometry ----
    int off[NSLOT];
#pragma unroll
    for (int s = 0; s < NSLOT; ++s) {
        int p = tid + s*256;
        if (p >= NPOS) p = NPOS - 1;
        int gy = refl(TY0 + p/HX - PAD, H_);
        int gx = refl(TX0 + p%HX - PAD, W_);
        off[s] = gy*W_ + gx;
    }
    const bool hasR = (tid < REM);

    // ---- prologue: issue group-0 stage loads ----
    float4 pv[NSLOT];
    {
        const float* xb = x + ((size_t)(b*C_ + c0))*HW;
#pragma unroll
        for (int s = 0; s < NSLOT; ++s) {
            if (s == NSLOT-1 && !hasR) break;
            pv[s].x = xb[0*HW + off[s]]; pv[s].y = xb[1*HW + off[s]];
            pv[s].z = xb[2*HW + off[s]]; pv[s].w = xb[3*HW + off[s]];
        }
    }

    // ---- per-pixel gating weights (overlaps with loads in flight) ----
    float wt[VPX][4];
#pragma unroll
    for (int p = 0; p < VPX; ++p) {
        float a = angle[((size_t)b*H_ + (y0+p))*W_ + wv];
        float s = __sinf(2.f*a), c = __cosf(2.f*a);
        float hv[8];
#pragma unroll
        for (int j = 0; j < 8; ++j) {
            float v = fmaf(s, w1[2*j], fmaf(c, w1[2*j+1], b1[j]));
            hv[j] = v > 0.f ? v : 0.f;
        }
        float lg[4];
#pragma unroll
        for (int d = 0; d < 4; ++d) {
            float v = b2[d];
#pragma unroll
            for (int j = 0; j < 8; ++j) v = fmaf(hv[j], w2[d*8+j], v);
            lg[d] = v;
        }
        float m  = fmaxf(fmaxf(lg[0], lg[1]), fmaxf(lg[2], lg[3]));
        float e0 = __expf(lg[0]-m), e1 = __expf(lg[1]-m);
        float e2 = __expf(lg[2]-m), e3 = __expf(lg[3]-m);
        float inv = 1.f / (e0+e1+e2+e3);
        wt[p][0] = e0*inv; wt[p][1] = e1*inv; wt[p][2] = e2*inv; wt[p][3] = e3*inv;
    }

    // ---- blend ONCE into 4 x 25 symmetric-unique VGPR taps ----
    float kb[VPX][25];
#pragma unroll
    for (int u = 0; u < 25; ++u) {
        const float s0 = kt.sk[0][u], s1 = kt.sk[1][u];
        const float s2 = kt.sk[2][u], s3 = kt.sk[3][u];
#pragma unroll
        for (int p = 0; p < VPX; ++p)
            kb[p][u] = wt[p][0]*s0 + wt[p][1]*s1 + wt[p][2]*s2 + wt[p][3]*s3;
    }

    // write group-0 tile
#pragma unroll
    for (int s = 0; s < NSLOT; ++s) {
        if (s == NSLOT-1 && !hasR) break;
        buf[0][tid + s*256] = pv[s];
    }

    for (int g = 0; g < NGRP; ++g) {
        __syncthreads();   // buf[g&1] ready; readers of buf[(g+1)&1] (iter g-1) done

        // issue next group's stage loads EARLY
        const bool doStage = (g + 1 < NGRP);
        if (doStage) {
            const float* xb = x + ((size_t)(b*C_ + c0 + (g+1)*NC))*HW;
#pragma unroll
            for (int s = 0; s < NSLOT; ++s) {
                if (s == NSLOT-1 && !hasR) break;
                pv[s].x = xb[0*HW + off[s]]; pv[s].y = xb[1*HW + off[s]];
                pv[s].z = xb[2*HW + off[s]]; pv[s].w = xb[3*HW + off[s]];
            }
        }

        // ---- conv: 4 vertical px x 4 channels, shared row reads ----
        const float4* tb = buf[g & 1];
        float4 acc[VPX];
#pragma unroll
        for (int p = 0; p < VPX; ++p) acc[p] = (float4){0.f,0.f,0.f,0.f};

#pragma unroll
        for (int r = 0; r < VPX + 6; ++r) {
            float4 win[7];
            const int base = (VPX*tr + r)*HX + tx;
#pragma unroll
            for (int j = 0; j < 7; ++j) win[j] = tb[base + j];
#pragma unroll
            for (int p = 0; p < VPX; ++p) {
                const int i = r - p;
                if (i < 0 || i > 6) continue;
#pragma unroll
                for (int j = 0; j < 7; ++j) {
                    const int t = i*7 + j;
                    const int u = (t <= 24) ? t : 48 - t;   // central symmetry
                    const float k = kb[p][u];
                    acc[p].x = fmaf(win[j].x, k, acc[p].x);
                    acc[p].y = fmaf(win[j].y, k, acc[p].y);
                    acc[p].z = fmaf(win[j].z, k, acc[p].z);
                    acc[p].w = fmaf(win[j].w, k, acc[p].w);
                }
            }
        }

        // ---- store 4 px x 4 ch ----
        float* ob = out + ((size_t)(b*C_ + c0 + g*NC))*HW + (size_t)y0*W_ + wv;
#pragma unroll
        for (int p = 0; p < VPX; ++p) {
            ob[p*W_ + 0*HW] = acc[p].x;
            ob[p*W_ + 1*HW] = acc[p].y;
            ob[p*W_ + 2*HW] = acc[p].z;
            ob[p*W_ + 3*HW] = acc[p].w;
        }

        // write-late: next group's tile into the other buffer
        if (doStage) {
            float4* nb = buf[(g+1) & 1];
#pragma unroll
            for (int s = 0; s < NSLOT; ++s) {
                if (s == NSLOT-1 && !hasR) break;
                nb[tid + s*256] = pv[s];
            }
        }
    }
}

static KTab make_ktab() {
    KTab t;
    const double sig1 = 2.5, sig2 = 1.0;
    const double angles[4] = {0.0, M_PI/4.0, M_PI/2.0, 3.0*M_PI/4.0};
    for (int d = 0; d < 4; ++d) {
        double th = angles[d], cs = cos(th), sn = sin(th);
        double sum = 0.0, k[7][7];
        for (int i = 0; i < 7; ++i) for (int j = 0; j < 7; ++j) {
            double xx = i - 3, yy = j - 3;
            double xr = xx*cs + yy*sn, yr = -xx*sn + yy*cs;
            k[i][j] = exp(-(xr*xr/(2.0*sig1*sig1) + yr*yr/(2.0*sig2*sig2)));
            sum += k[i][j];
        }
        for (int u = 0; u < 25; ++u)
            t.sk[d][u] = (float)(k[u/7][u%7]/sum);
    }
    return t;
}

extern "C" void kernel_launch(void* const* d_in, const int* in_sizes, int n_in,
                              void* d_out, int out_size, void* d_ws, size_t ws_size,
                              hipStream_t stream) {
    const float* x     = (const float*)d_in[0];
    const float* angle = (const float*)d_in[1];
    const float* w1    = (const float*)d_in[2];
    const float* b1    = (const float*)d_in[3];
    const float* w2    = (const float*)d_in[4];
    const float* b2    = (const float*)d_in[5];
    float* out = (float*)d_out;

    static const KTab kt = make_ktab();   // deterministic; host-side, no HIP calls

    dim3 grid((W_/TX)*(H_/TY), B_, NCHUNK);   // 16 x 8 x 4 = 512 blocks
    dim3 block(256);
    ddconv_kernel<<<grid, block, 0, stream>>>(x, angle, w1, b1, w2, b2, out, kt);
}